// Round 1
// baseline (1037.647 us; speedup 1.0000x reference)
//
#include <hip/hip_runtime.h>
#include <math.h>

#define S_LEN  2048
#define BATCH  2
#define DMODEL 1024
#define NHEAD  16
#define DHEAD  64
#define M_ROWS (S_LEN * BATCH)   // 4096
#define EQKV   3072              // q(1024) + k(1024) + v(1024) columns in Y
#define LN_EPSF 1e-5f

// ---------------------------------------------------------------------------
// GEMM: C[bm..][ccol0+bn..] = A[M][K] * W[N][K]^T   (both A and W are K-major)
// 128x128 tile, BK=16, 256 threads, 8x8 micro-tile split as (4+4)x(4+4)
// so LDS reads are 16B-stride -> only 2-way bank aliasing (free).
// ---------------------------------------------------------------------------
#define GBM 128
#define GBN 128
#define GBK 16

__global__ __launch_bounds__(256, 2)
void gemm_abt(const float* __restrict__ A, const float* __restrict__ W,
              float* __restrict__ C, int K, int ldc, int ccol0)
{
    __shared__ float As[GBK][GBM + 4];
    __shared__ float Bs[GBK][GBN + 4];

    const int bm  = blockIdx.y * GBM;
    const int bn  = blockIdx.x * GBN;
    const int tid = threadIdx.x;
    const int tr  = tid >> 4;    // 0..15 -> rows tr*4 and 64+tr*4
    const int tc  = tid & 15;    // 0..15 -> cols tc*4 and 64+tc*4

    float acc[8][8];
#pragma unroll
    for (int i = 0; i < 8; ++i)
#pragma unroll
        for (int j = 0; j < 8; ++j) acc[i][j] = 0.f;

    for (int k0 = 0; k0 < K; k0 += GBK) {
#pragma unroll
        for (int l = 0; l < 2; ++l) {
            const int idx = tid + l * 256;       // 0..511 float4 slots
            const int row = idx >> 2;            // 0..127
            const int kk  = (idx & 3) << 2;      // 0,4,8,12
            const float4 av = *(const float4*)&A[(size_t)(bm + row) * K + k0 + kk];
            As[kk + 0][row] = av.x; As[kk + 1][row] = av.y;
            As[kk + 2][row] = av.z; As[kk + 3][row] = av.w;
            const float4 bv = *(const float4*)&W[(size_t)(bn + row) * K + k0 + kk];
            Bs[kk + 0][row] = bv.x; Bs[kk + 1][row] = bv.y;
            Bs[kk + 2][row] = bv.z; Bs[kk + 3][row] = bv.w;
        }
        __syncthreads();

#pragma unroll
        for (int k = 0; k < GBK; ++k) {
            float a[8], b[8];
            *(float4*)&a[0] = *(const float4*)&As[k][tr * 4];
            *(float4*)&a[4] = *(const float4*)&As[k][64 + tr * 4];
            *(float4*)&b[0] = *(const float4*)&Bs[k][tc * 4];
            *(float4*)&b[4] = *(const float4*)&Bs[k][64 + tc * 4];
#pragma unroll
            for (int i = 0; i < 8; ++i)
#pragma unroll
                for (int j = 0; j < 8; ++j)
                    acc[i][j] = fmaf(a[i], b[j], acc[i][j]);
        }
        __syncthreads();
    }

#pragma unroll
    for (int i = 0; i < 8; ++i) {
        const int row = bm + ((i < 4) ? (tr * 4 + i) : (64 + tr * 4 + i - 4));
        float* crow = &C[(size_t)row * ldc + ccol0 + bn];
        *(float4*)&crow[tc * 4]      = make_float4(acc[i][0], acc[i][1], acc[i][2], acc[i][3]);
        *(float4*)&crow[64 + tc * 4] = make_float4(acc[i][4], acc[i][5], acc[i][6], acc[i][7]);
    }
}

// ---------------------------------------------------------------------------
// Flash attention, fp32. One WG per (i-tile of 64 rows, b, n).
// Y holds [4096][3072] = q | k | v. Writes attn_vec [4096][1024].
// ---------------------------------------------------------------------------
__global__ __launch_bounds__(256, 2)
void attn_kernel(const float* __restrict__ Y, float* __restrict__ attn_vec)
{
    const int it  = blockIdx.x;        // 0..31 (i tile)
    const int b   = blockIdx.y >> 4;   // 0..1
    const int n   = blockIdx.y & 15;   // 0..15
    const int tid = threadIdx.x;
    const int ti  = tid >> 4;          // 0..15 -> i rows ti*4..ti*4+3
    const int tc  = tid & 15;          // 0..15 -> j / d cols tc*4..tc*4+3

    __shared__ float Qs[DHEAD][64 + 4];   // [d][i]
    __shared__ float Ks[DHEAD][64 + 4];   // [d][j]; reused as Ps[j][i]
    __shared__ float Vs[64][DHEAD + 4];   // [j][d]

    const float scale = 0.125f;           // 1/sqrt(64)
    const size_t srow = (size_t)BATCH * EQKV;   // stride between consecutive s
    const size_t base = (size_t)b * EQKV + (size_t)n * DHEAD;

    // Load Q tile transposed: Qs[d][i]
#pragma unroll
    for (int l = 0; l < 4; ++l) {
        const int f   = tid + l * 256;   // 0..1023 float4 slots
        const int row = f >> 4;          // 0..63
        const int d4  = (f & 15) << 2;   // 0..60
        const float4 v = *(const float4*)&Y[(size_t)(it * 64 + row) * srow + base + d4];
        Qs[d4 + 0][row] = v.x; Qs[d4 + 1][row] = v.y;
        Qs[d4 + 2][row] = v.z; Qs[d4 + 3][row] = v.w;
    }

    float o[4][4];
    float m[4], lsum[4];
#pragma unroll
    for (int i = 0; i < 4; ++i) {
        m[i] = -INFINITY; lsum[i] = 0.f;
#pragma unroll
        for (int j = 0; j < 4; ++j) o[i][j] = 0.f;
    }

    for (int jt = 0; jt < S_LEN / 64; ++jt) {
        // Load K (transposed) and V (row-major)
#pragma unroll
        for (int l = 0; l < 4; ++l) {
            const int f   = tid + l * 256;
            const int row = f >> 4;
            const int d4  = (f & 15) << 2;
            const size_t roff = (size_t)(jt * 64 + row) * srow + base;
            const float4 kv4 = *(const float4*)&Y[roff + 1024 + d4];
            Ks[d4 + 0][row] = kv4.x; Ks[d4 + 1][row] = kv4.y;
            Ks[d4 + 2][row] = kv4.z; Ks[d4 + 3][row] = kv4.w;
            const float4 vv4 = *(const float4*)&Y[roff + 2048 + d4];
            *(float4*)&Vs[row][d4] = vv4;
        }
        __syncthreads();

        // S = scale * Q K^T  (4x4 per thread)
        float s[4][4];
#pragma unroll
        for (int i = 0; i < 4; ++i)
#pragma unroll
            for (int j = 0; j < 4; ++j) s[i][j] = 0.f;

#pragma unroll 8
        for (int d = 0; d < DHEAD; ++d) {
            const float4 qa = *(const float4*)&Qs[d][ti * 4];
            const float4 kb = *(const float4*)&Ks[d][tc * 4];
            const float a0[4] = {qa.x, qa.y, qa.z, qa.w};
            const float b0[4] = {kb.x, kb.y, kb.z, kb.w};
#pragma unroll
            for (int i = 0; i < 4; ++i)
#pragma unroll
                for (int j = 0; j < 4; ++j)
                    s[i][j] = fmaf(a0[i], b0[j], s[i][j]);
        }

        // online softmax update per row
#pragma unroll
        for (int i = 0; i < 4; ++i) {
            float rmax = s[i][0];
#pragma unroll
            for (int j = 1; j < 4; ++j) rmax = fmaxf(rmax, s[i][j]);
            rmax *= scale;
#pragma unroll
            for (int off = 1; off < 16; off <<= 1)
                rmax = fmaxf(rmax, __shfl_xor(rmax, off));
            const float mn   = fmaxf(m[i], rmax);
            const float corr = __expf(m[i] - mn);
            float ps = 0.f;
#pragma unroll
            for (int j = 0; j < 4; ++j) {
                s[i][j] = __expf(fmaf(s[i][j], scale, -mn));
                ps += s[i][j];
            }
#pragma unroll
            for (int off = 1; off < 16; off <<= 1) ps += __shfl_xor(ps, off);
            lsum[i] = lsum[i] * corr + ps;
            m[i] = mn;
#pragma unroll
            for (int d = 0; d < 4; ++d) o[i][d] *= corr;
        }
        __syncthreads();   // everyone done reading Ks

        // stash P transposed into Ks: Ps[j][i]
#pragma unroll
        for (int i = 0; i < 4; ++i)
#pragma unroll
            for (int j = 0; j < 4; ++j)
                Ks[tc * 4 + j][ti * 4 + i] = s[i][j];
        __syncthreads();

        // O += P V
#pragma unroll 8
        for (int j = 0; j < 64; ++j) {
            const float4 pa = *(const float4*)&Ks[j][ti * 4];
            const float4 vb = *(const float4*)&Vs[j][tc * 4];
            const float p0[4] = {pa.x, pa.y, pa.z, pa.w};
            const float v0[4] = {vb.x, vb.y, vb.z, vb.w};
#pragma unroll
            for (int i = 0; i < 4; ++i)
#pragma unroll
                for (int d = 0; d < 4; ++d)
                    o[i][d] = fmaf(p0[i], v0[d], o[i][d]);
        }
        __syncthreads();   // before next tile overwrites Ks/Vs
    }

    // finalize + store
#pragma unroll
    for (int i = 0; i < 4; ++i) {
        const float inv = 1.f / lsum[i];
        const int   srow_i = it * 64 + ti * 4 + i;
        float* dst = &attn_vec[(size_t)(srow_i * BATCH + b) * DMODEL + n * DHEAD + tc * 4];
        *(float4*)dst = make_float4(o[i][0] * inv, o[i][1] * inv, o[i][2] * inv, o[i][3] * inv);
    }
}

// ---------------------------------------------------------------------------
// Residual + LayerNorm. One WG (256 thr) per row of 1024.
// ---------------------------------------------------------------------------
__global__ __launch_bounds__(256)
void ln_kernel(const float* __restrict__ h, const float* __restrict__ ao,
               const float* __restrict__ g, const float* __restrict__ beta,
               float* __restrict__ out)
{
    __shared__ float red[4];
    const int r   = blockIdx.x;
    const int tid = threadIdx.x;
    const int c   = tid * 4;
    const size_t off = (size_t)r * DMODEL + c;

    const float4 xv = *(const float4*)&h[off];
    const float4 av = *(const float4*)&ao[off];
    float x[4] = {xv.x + av.x, xv.y + av.y, xv.z + av.z, xv.w + av.w};

    // pass 1: mean
    float s = x[0] + x[1] + x[2] + x[3];
#pragma unroll
    for (int o2 = 1; o2 < 64; o2 <<= 1) s += __shfl_xor(s, o2);
    if ((tid & 63) == 0) red[tid >> 6] = s;
    __syncthreads();
    const float mean = (red[0] + red[1] + red[2] + red[3]) * (1.f / DMODEL);
    __syncthreads();

    // pass 2: variance (matches reference formula exactly)
    float d0 = x[0] - mean, d1 = x[1] - mean, d2 = x[2] - mean, d3 = x[3] - mean;
    float vs = d0 * d0 + d1 * d1 + d2 * d2 + d3 * d3;
#pragma unroll
    for (int o2 = 1; o2 < 64; o2 <<= 1) vs += __shfl_xor(vs, o2);
    if ((tid & 63) == 0) red[tid >> 6] = vs;
    __syncthreads();
    const float var  = (red[0] + red[1] + red[2] + red[3]) * (1.f / DMODEL);
    const float rstd = rsqrtf(var + LN_EPSF);

    const float4 gv = *(const float4*)&g[c];
    const float4 bv = *(const float4*)&beta[c];
    float4 ov;
    ov.x = d0 * rstd * gv.x + bv.x;
    ov.y = d1 * rstd * gv.y + bv.y;
    ov.z = d2 * rstd * gv.z + bv.z;
    ov.w = d3 * rstd * gv.w + bv.w;
    *(float4*)&out[off] = ov;
}

// ---------------------------------------------------------------------------
extern "C" void kernel_launch(void* const* d_in, const int* in_sizes, int n_in,
                              void* d_out, int out_size, void* d_ws, size_t ws_size,
                              hipStream_t stream)
{
    const float* h   = (const float*)d_in[0];
    const float* Wq  = (const float*)d_in[1];
    const float* Wkv = (const float*)d_in[2];
    const float* Wo  = (const float*)d_in[3];
    const float* g   = (const float*)d_in[4];
    const float* bb  = (const float*)d_in[5];
    float* out = (float*)d_out;

    float* Y        = (float*)d_ws;                           // [4096][3072] qkv
    float* attn_vec = Y + (size_t)M_ROWS * EQKV;              // [4096][1024]
    float* attn_out = attn_vec + (size_t)M_ROWS * DMODEL;     // [4096][1024]

    const dim3 blk(256);

    // QKV projection: Y[:, :1024] = h Wq^T ; Y[:, 1024:] = h Wkv^T
    gemm_abt<<<dim3(1024 / GBN, M_ROWS / GBM), blk, 0, stream>>>(h, Wq,  Y, DMODEL, EQKV, 0);
    gemm_abt<<<dim3(2048 / GBN, M_ROWS / GBM), blk, 0, stream>>>(h, Wkv, Y, DMODEL, EQKV, 1024);

    // attention
    attn_kernel<<<dim3(S_LEN / 64, BATCH * NHEAD), blk, 0, stream>>>(Y, attn_vec);

    // output projection
    gemm_abt<<<dim3(1024 / GBN, M_ROWS / GBM), blk, 0, stream>>>(attn_vec, Wo, attn_out, DMODEL, DMODEL, 0);

    // residual + layernorm
    ln_kernel<<<dim3(M_ROWS), blk, 0, stream>>>(h, attn_out, g, bb, out);
}

// Round 3
// 277.058 us; speedup vs baseline: 3.7452x; 3.7452x over previous
//
#include <hip/hip_runtime.h>
#include <math.h>

#define S_LEN  2048
#define BATCH  2
#define DMODEL 1024
#define NHEAD  16
#define DHEAD  64
#define M_ROWS 4096
#define EQKV   3072
#define LN_EPSF 1e-5f

typedef __attribute__((ext_vector_type(8))) __bf16 bf16x8;
typedef __attribute__((ext_vector_type(8))) unsigned short u16x8;
typedef __attribute__((ext_vector_type(4))) float f32x4;

#define MFMA16(a, b, c) __builtin_amdgcn_mfma_f32_16x16x32_bf16((a), (b), (c), 0, 0, 0)

// global -> LDS direct copy, 16B per lane; LDS dest must be wave-uniform base.
#define GLD_LDS16(gp, lp)                                                      \
  __builtin_amdgcn_global_load_lds(                                            \
      (const __attribute__((address_space(1))) void*)(gp),                     \
      (__attribute__((address_space(3))) void*)(lp), 16, 0, 0)

__device__ __forceinline__ unsigned short f2bf(float f) {
  unsigned int u = __float_as_uint(f);
  u += 0x7fffu + ((u >> 16) & 1u);   // round-to-nearest-even
  return (unsigned short)(u >> 16);
}

// ---------------------------------------------------------------------------
// fp32 -> bf16 conversion (vectorized, memory-bound)
// ---------------------------------------------------------------------------
__global__ __launch_bounds__(256)
void cvt_bf16(const float* __restrict__ in, unsigned short* __restrict__ out, int n4)
{
  const int i = blockIdx.x * 256 + threadIdx.x;
  if (i >= n4) return;
  const float4 v = ((const float4*)in)[i];
  ushort4 o;
  o.x = f2bf(v.x); o.y = f2bf(v.y); o.z = f2bf(v.z); o.w = f2bf(v.w);
  ((ushort4*)out)[i] = o;
}

// ---------------------------------------------------------------------------
// bf16 MFMA GEMM: C[bm..][n0..] = A[M][K] * W[N][K]^T
// 128x128 tile, BK=64, 4 waves (2x2), 16x16x32 MFMA.
// LDS tiles [128 rows][64 cols] bf16 (128B rows), XOR-swizzled: the 16B slot
// holding k-chunk g of row r lives at slot g^(r&7). global_load_lds writes
// linearly, so the GLOBAL source column-slot is pre-swizzled (involution).
// W1 (if non-null) supplies output columns >= 1024 (fused Wq|Wkv launch).
// ---------------------------------------------------------------------------
template<bool OUT_BF16>
__global__ __launch_bounds__(256)
void gemm_mfma(const unsigned short* __restrict__ A,
               const unsigned short* __restrict__ W0,
               const unsigned short* __restrict__ W1,
               void* __restrict__ Cp, int K, int ldc)
{
  __shared__ unsigned short As[128 * 64];
  __shared__ unsigned short Ws[128 * 64];

  const int bm = blockIdx.y * 128;
  const int n0 = blockIdx.x * 128;
  const unsigned short* W = (W1 != nullptr && n0 >= 1024)
                              ? (W1 + (size_t)(n0 - 1024) * K)
                              : (W0 + (size_t)n0 * K);

  const int tid  = threadIdx.x;
  const int lane = tid & 63;
  const int w    = tid >> 6;
  const int lo   = lane & 15, hi = lane >> 4;
  const int wr   = w >> 1, wc = w & 1;

  f32x4 acc[4][4];
#pragma unroll
  for (int i = 0; i < 4; ++i)
#pragma unroll
    for (int j = 0; j < 4; ++j) acc[i][j] = (f32x4)0.f;

  const int str = tid >> 3;   // staging row base 0..31
  const int ssl = tid & 7;    // staging slot

  for (int k0 = 0; k0 < K; k0 += 64) {
#pragma unroll
    for (int l = 0; l < 4; ++l) {
      const int row = str + l * 32;
      const int cs  = ssl ^ (row & 7);            // pre-swizzled source slot
      GLD_LDS16(A + (size_t)(bm + row) * K + k0 + cs * 8,
                (char*)As + l * 4096 + w * 1024);
      GLD_LDS16(W + (size_t)row * K + k0 + cs * 8,
                (char*)Ws + l * 4096 + w * 1024);
    }
    __syncthreads();

#pragma unroll
    for (int ks = 0; ks < 2; ++ks) {
      bf16x8 af[4], bw[4];
#pragma unroll
      for (int i = 0; i < 4; ++i) {
        const int row = wr * 64 + i * 16 + lo;
        af[i] = *(const bf16x8*)&As[row * 64 + (((ks * 4 + hi) ^ (row & 7)) * 8)];
      }
#pragma unroll
      for (int j = 0; j < 4; ++j) {
        const int row = wc * 64 + j * 16 + lo;
        bw[j] = *(const bf16x8*)&Ws[row * 64 + (((ks * 4 + hi) ^ (row & 7)) * 8)];
      }
#pragma unroll
      for (int i = 0; i < 4; ++i)
#pragma unroll
        for (int j = 0; j < 4; ++j)
          acc[i][j] = MFMA16(af[i], bw[j], acc[i][j]);
    }
    __syncthreads();
  }

  // epilogue: C/D layout col = lane&15, row = (lane>>4)*4 + reg
#pragma unroll
  for (int i = 0; i < 4; ++i)
#pragma unroll
    for (int j = 0; j < 4; ++j)
#pragma unroll
      for (int r = 0; r < 4; ++r) {
        const int row = bm + wr * 64 + i * 16 + hi * 4 + r;
        const int col = n0 + wc * 64 + j * 16 + lo;
        if constexpr (OUT_BF16)
          ((unsigned short*)Cp)[(size_t)row * ldc + col] = f2bf(acc[i][j][r]);
        else
          ((float*)Cp)[(size_t)row * ldc + col] = acc[i][j][r];
      }
}

// ---------------------------------------------------------------------------
// Flash attention, bf16 MFMA. Block = 256 thr = 4 waves; wave w owns q-rows
// it*64 + w*16 .. +16. BJ=64 per iteration. Softmax state rows coincide with
// MFMA C-layout rows (hi*4+r) for both S and O accumulators.
// ---------------------------------------------------------------------------
__global__ __launch_bounds__(256)
void attn_mfma(const unsigned short* __restrict__ Y, unsigned short* __restrict__ av)
{
  __shared__ unsigned short Kl[64 * 64];   // K tile  [j][d]  swizzled rows
  __shared__ unsigned short Vl[64 * 64];   // V^T     [d][j]  swizzled rows
  __shared__ unsigned short Pl[64 * 64];   // P tile  [q][j]  swizzled rows (per-wave slabs)

  const int it   = blockIdx.x;
  const int b    = blockIdx.y >> 4;
  const int n    = blockIdx.y & 15;
  const int tid  = threadIdx.x;
  const int lane = tid & 63;
  const int w    = tid >> 6;
  const int lo   = lane & 15, hi = lane >> 4;

  // Q fragments (A operand): rows w*16+lo, k-chunks ks*32 + hi*8
  bf16x8 qf[2];
  {
    const size_t m = (size_t)((it * 64 + w * 16 + lo) * BATCH + b);
    const unsigned short* qp = Y + m * EQKV + n * DHEAD + hi * 8;
    qf[0] = *(const bf16x8*)qp;
    qf[1] = *(const bf16x8*)(qp + 32);
  }

  f32x4 of[4];
  float m_r[4], l_r[4];
#pragma unroll
  for (int x = 0; x < 4; ++x) { of[x] = (f32x4)0.f; m_r[x] = -INFINITY; l_r[x] = 0.f; }

  const int vj  = lane;      // V staging: this lane's j-row
  const int vd0 = w * 16;    // wave-uniform d block

  for (int jt = 0; jt < S_LEN / 64; ++jt) {
    // --- stage K via global_load_lds, pre-swizzled source ---
#pragma unroll
    for (int l = 0; l < 2; ++l) {
      const int row = (tid >> 3) + l * 32;
      const int cs  = (tid & 7) ^ (row & 7);
      GLD_LDS16(Y + (size_t)((jt * 64 + row) * BATCH + b) * EQKV + DMODEL + n * DHEAD + cs * 8,
                (char*)Kl + l * 4096 + w * 1024);
    }
    // --- stage V transposed (Vt[d][j]), swizzled by d; writes conflict-free ---
    {
      const unsigned short* gv =
          Y + (size_t)((jt * 64 + vj) * BATCH + b) * EQKV + 2 * DMODEL + n * DHEAD + vd0;
      const u16x8 v0 = *(const u16x8*)gv;
      const u16x8 v1 = *(const u16x8*)(gv + 8);
#pragma unroll
      for (int e = 0; e < 8; ++e) {
        const int d0 = vd0 + e, d1 = vd0 + 8 + e;
        Vl[d0 * 64 + (((vj >> 3) ^ (d0 & 7)) * 8) + (vj & 7)] = v0[e];
        Vl[d1 * 64 + (((vj >> 3) ^ (d1 & 7)) * 8) + (vj & 7)] = v1[e];
      }
    }
    __syncthreads();

    // --- S = Q K^T (rows hi*4+r, cols jf*16+lo) ---
    f32x4 sf[4];
#pragma unroll
    for (int jf = 0; jf < 4; ++jf) sf[jf] = (f32x4)0.f;
#pragma unroll
    for (int ks = 0; ks < 2; ++ks)
#pragma unroll
      for (int jf = 0; jf < 4; ++jf) {
        const int row = jf * 16 + lo;
        const bf16x8 kf = *(const bf16x8*)&Kl[row * 64 + (((ks * 4 + hi) ^ (row & 7)) * 8)];
        sf[jf] = MFMA16(qf[ks], kf, sf[jf]);
      }

    // --- online softmax (scale 0.125 folded into exp) ---
    float rmx[4];
#pragma unroll
    for (int r = 0; r < 4; ++r) {
      rmx[r] = fmaxf(fmaxf(sf[0][r], sf[1][r]), fmaxf(sf[2][r], sf[3][r]));
#pragma unroll
      for (int msk = 1; msk < 16; msk <<= 1)
        rmx[r] = fmaxf(rmx[r], __shfl_xor(rmx[r], msk));
    }
#pragma unroll
    for (int r = 0; r < 4; ++r) {
      const float mn   = fmaxf(m_r[r], rmx[r] * 0.125f);
      const float corr = __expf(m_r[r] - mn);
      float ps = 0.f;
#pragma unroll
      for (int jf = 0; jf < 4; ++jf) {
        const float p = __expf(fmaf(sf[jf][r], 0.125f, -mn));
        sf[jf][r] = p;
        ps += p;
      }
#pragma unroll
      for (int msk = 1; msk < 16; msk <<= 1) ps += __shfl_xor(ps, msk);
      l_r[r] = l_r[r] * corr + ps;
      m_r[r] = mn;
#pragma unroll
      for (int df = 0; df < 4; ++df) of[df][r] *= corr;
    }

    // --- write P (bf16) to this wave's private slab ---
#pragma unroll
    for (int jf = 0; jf < 4; ++jf)
#pragma unroll
      for (int r = 0; r < 4; ++r) {
        const int prow = w * 16 + hi * 4 + r;
        const int j    = jf * 16 + lo;
        Pl[prow * 64 + (((j >> 3) ^ (prow & 7)) * 8) + (j & 7)] = f2bf(sf[jf][r]);
      }

    // --- O += P V ---
#pragma unroll
    for (int js = 0; js < 2; ++js) {
      const int prow = w * 16 + lo;
      const bf16x8 pa = *(const bf16x8*)&Pl[prow * 64 + (((js * 4 + hi) ^ (prow & 7)) * 8)];
#pragma unroll
      for (int df = 0; df < 4; ++df) {
        const int d = df * 16 + lo;
        const bf16x8 vb = *(const bf16x8*)&Vl[d * 64 + (((js * 4 + hi) ^ (d & 7)) * 8)];
        of[df] = MFMA16(pa, vb, of[df]);
      }
    }
    __syncthreads();   // before next tile's staging overwrites Kl/Vl
  }

  // --- finalize + store bf16 attn_vec ---
#pragma unroll
  for (int df = 0; df < 4; ++df)
#pragma unroll
    for (int r = 0; r < 4; ++r) {
      const size_t m = (size_t)((it * 64 + w * 16 + hi * 4 + r) * BATCH + b);
      av[m * DMODEL + n * DHEAD + df * 16 + lo] = f2bf(of[df][r] / l_r[r]);
    }
}

// ---------------------------------------------------------------------------
// Residual + LayerNorm (fp32, exact reference formula). One WG per row.
// ---------------------------------------------------------------------------
__global__ __launch_bounds__(256)
void ln_kernel(const float* __restrict__ h, const float* __restrict__ ao,
               const float* __restrict__ g, const float* __restrict__ beta,
               float* __restrict__ out)
{
  __shared__ float red[4];
  const int r   = blockIdx.x;
  const int tid = threadIdx.x;
  const int c   = tid * 4;
  const size_t off = (size_t)r * DMODEL + c;

  const float4 xv = *(const float4*)&h[off];
  const float4 av = *(const float4*)&ao[off];
  float x[4] = {xv.x + av.x, xv.y + av.y, xv.z + av.z, xv.w + av.w};

  float s = x[0] + x[1] + x[2] + x[3];
#pragma unroll
  for (int o2 = 1; o2 < 64; o2 <<= 1) s += __shfl_xor(s, o2);
  if ((tid & 63) == 0) red[tid >> 6] = s;
  __syncthreads();
  const float mean = (red[0] + red[1] + red[2] + red[3]) * (1.f / DMODEL);
  __syncthreads();

  float d0 = x[0] - mean, d1 = x[1] - mean, d2 = x[2] - mean, d3 = x[3] - mean;
  float vs = d0 * d0 + d1 * d1 + d2 * d2 + d3 * d3;
#pragma unroll
  for (int o2 = 1; o2 < 64; o2 <<= 1) vs += __shfl_xor(vs, o2);
  if ((tid & 63) == 0) red[tid >> 6] = vs;
  __syncthreads();
  const float var  = (red[0] + red[1] + red[2] + red[3]) * (1.f / DMODEL);
  const float rstd = rsqrtf(var + LN_EPSF);

  const float4 gv = *(const float4*)&g[c];
  const float4 bv = *(const float4*)&beta[c];
  float4 ov;
  ov.x = d0 * rstd * gv.x + bv.x;
  ov.y = d1 * rstd * gv.y + bv.y;
  ov.z = d2 * rstd * gv.z + bv.z;
  ov.w = d3 * rstd * gv.w + bv.w;
  *(float4*)&out[off] = ov;
}

// ---------------------------------------------------------------------------
extern "C" void kernel_launch(void* const* d_in, const int* in_sizes, int n_in,
                              void* d_out, int out_size, void* d_ws, size_t ws_size,
                              hipStream_t stream)
{
  const float* h   = (const float*)d_in[0];
  const float* Wq  = (const float*)d_in[1];
  const float* Wkv = (const float*)d_in[2];
  const float* Wo  = (const float*)d_in[3];
  const float* g   = (const float*)d_in[4];
  const float* bb  = (const float*)d_in[5];
  float* out = (float*)d_out;

  char* ws = (char*)d_ws;
  unsigned short* hb   = (unsigned short*)(ws);                    //  8 MB  h bf16
  unsigned short* wqb  = (unsigned short*)(ws + (8u  << 20));      //  2 MB
  unsigned short* wkvb = (unsigned short*)(ws + (10u << 20));      //  4 MB
  unsigned short* wob  = (unsigned short*)(ws + (14u << 20));      //  2 MB
  unsigned short* Y    = (unsigned short*)(ws + (16u << 20));      // 24 MB  qkv bf16
  unsigned short* av   = (unsigned short*)(ws + (40u << 20));      //  8 MB  attn_vec bf16
  float*          ao   = (float*)        (ws + (48u << 20));       // 16 MB  attn_out fp32

  // bf16 casts
  cvt_bf16<<<4096, 256, 0, stream>>>(h,   hb,   (M_ROWS * DMODEL) / 4);
  cvt_bf16<<<1024, 256, 0, stream>>>(Wq,  wqb,  (1024 * DMODEL) / 4);
  cvt_bf16<<<2048, 256, 0, stream>>>(Wkv, wkvb, (2048 * DMODEL) / 4);
  cvt_bf16<<<1024, 256, 0, stream>>>(Wo,  wob,  (1024 * DMODEL) / 4);

  // fused QKV projection: Y[:, 0:1024] = h Wq^T ; Y[:, 1024:3072] = h Wkv^T
  gemm_mfma<true><<<dim3(EQKV / 128, M_ROWS / 128), 256, 0, stream>>>(
      hb, wqb, wkvb, (void*)Y, DMODEL, EQKV);

  // attention
  attn_mfma<<<dim3(S_LEN / 64, BATCH * NHEAD), 256, 0, stream>>>(Y, av);

  // output projection (fp32 out)
  gemm_mfma<false><<<dim3(DMODEL / 128, M_ROWS / 128), 256, 0, stream>>>(
      av, wob, nullptr, (void*)ao, DMODEL, DMODEL);

  // residual + layernorm
  ln_kernel<<<M_ROWS, 256, 0, stream>>>(h, ao, g, bb, out);
}